// Round 1
// baseline (20331.882 us; speedup 1.0000x reference)
//
#include <hip/hip_runtime.h>
#include <cmath>

#define S_DIM 64
#define B_DIM 32
#define L_DIM 64
#define NMSG  2048        // S*B
#define D_DIM 300
#define HH    256         // word-LSTM hidden per direction
#define HC    512         // conv-LSTM hidden
#define F_DIM 16
#define KW    556         // D_DIM + HH

// ---- workspace layout (float offsets) ----
#define OFF_HF  0u
#define OFF_CF  524288u          // 2048*256
#define OFF_HB  1048576u
#define OFF_CB  1572864u
#define OFF_ENC 2097152u         // 2048*512 (runmax/enc) [n*512 + dir*256 + j]
#define OFF_CH  3145728u         // 32*512 conv h
#define OFF_CC  3162112u         // 32*512 conv c
#define OFF_CO  3178496u         // 64*32*512 conv_out
#define OFF_LEN 4227072u         // 2048 ints (msg_len), stored in float slots
#define INIT_COUNT 3178496u      // elements init'd each call (h/c/enc/convh/convc)

__device__ __forceinline__ float sigm(float x) { return 1.0f / (1.0f + expf(-x)); }

// ---------------- init ----------------
__global__ __launch_bounds__(256) void init_ws(float* __restrict__ ws) {
    unsigned i = blockIdx.x * 256u + threadIdx.x;
    if (i < INIT_COUNT) {
        float v = (i >= OFF_ENC && i < OFF_CH) ? -INFINITY : 0.0f;
        ws[i] = v;
    }
}

// ---------------- msg_len ----------------
__global__ __launch_bounds__(256) void msg_len_kernel(const int* __restrict__ msgs,
                                                      int* __restrict__ mlen) {
    int n = blockIdx.x * 256 + threadIdx.x;
    if (n >= NMSG) return;
    int cnt = 0;
    #pragma unroll 8
    for (int l = 0; l < L_DIM; ++l) cnt += (msgs[n * L_DIM + l] != 0);
    mlen[n] = max(cnt, 1);
}

// ---------------- word-level LSTM step (both directions) ----------------
// grid: (32 n-tiles, 8 j-tiles, 2 dirs), block 256
// tile: 64 msgs x 32 j (x4 gates). thread: 4 n x 2 j x 4 g accumulators.
__global__ __launch_bounds__(256) void word_step(
    const int* __restrict__ msgs, const int* __restrict__ mlen,
    const float* __restrict__ E,
    const float* __restrict__ Wih_f, const float* __restrict__ Whh_f, const float* __restrict__ bf_,
    const float* __restrict__ Wih_b, const float* __restrict__ Whh_b, const float* __restrict__ bb_,
    float* __restrict__ ws, int t)
{
    const int dir = blockIdx.z;
    const float* Wih  = dir ? Wih_b : Wih_f;
    const float* Whh  = dir ? Whh_b : Whh_f;
    const float* bias = dir ? bb_   : bf_;
    float* h   = ws + (dir ? OFF_HB : OFF_HF);
    float* c   = ws + (dir ? OFF_CB : OFF_CF);
    float* enc = ws + OFF_ENC;

    __shared__ float As[64][17];        // padded: stride 17 breaks bank conflicts
    __shared__ float Wsm[16][32][5];    // [k][j][gate] padded g-dim
    __shared__ int   tok_s[64];
    __shared__ int   len_s[64];

    const int tid = threadIdx.x;
    const int n0 = blockIdx.x * 64;
    const int j0 = blockIdx.y * 32;

    if (tid < 64) {
        int n = n0 + tid;
        int len = mlen[n];
        len_s[tid] = len;
        int tt = dir ? (len - 1 - t) : t;
        if (t >= len) tt = 0;            // invalid step: gather any valid row
        tok_s[tid] = msgs[n * L_DIM + tt];
    }
    __syncthreads();

    const int ng = tid & 15;    // n-group (x4 rows)
    const int jg = tid >> 4;    // j-group (x2 cols)

    float acc[4][8];
    #pragma unroll
    for (int a = 0; a < 4; ++a)
        #pragma unroll
        for (int bq = 0; bq < 8; ++bq) acc[a][bq] = 0.0f;

    for (int k0 = 0; k0 < 560; k0 += 16) {
        // stage A: 64 n x 16 k
        #pragma unroll
        for (int i = tid; i < 1024; i += 256) {
            int nl = i >> 4, kl = i & 15;
            int k = k0 + kl;
            float v = 0.0f;
            if (k < D_DIM)      v = E[tok_s[nl] * D_DIM + k];
            else if (k < KW)    v = h[(n0 + nl) * HH + (k - D_DIM)];
            As[nl][kl] = v;
        }
        // stage W: 16 k x 32 j x 4 g
        {
            int r = tid >> 1, half = tid & 1;
            int jl = r >> 2, g = r & 3;
            int row = g * 256 + j0 + jl;
            #pragma unroll
            for (int u = 0; u < 8; ++u) {
                int kl = half * 8 + u;
                int k = k0 + kl;
                float w = 0.0f;
                if (k < D_DIM)    w = Wih[row * D_DIM + k];
                else if (k < KW)  w = Whh[row * HH + (k - D_DIM)];
                Wsm[kl][jl][g] = w;
            }
        }
        __syncthreads();
        #pragma unroll
        for (int kl = 0; kl < 16; ++kl) {
            float a0 = As[ng * 4 + 0][kl];
            float a1 = As[ng * 4 + 1][kl];
            float a2 = As[ng * 4 + 2][kl];
            float a3 = As[ng * 4 + 3][kl];
            #pragma unroll
            for (int jj = 0; jj < 2; ++jj) {
                #pragma unroll
                for (int g = 0; g < 4; ++g) {
                    float w = Wsm[kl][jg * 2 + jj][g];
                    acc[0][jj * 4 + g] += a0 * w;
                    acc[1][jj * 4 + g] += a1 * w;
                    acc[2][jj * 4 + g] += a2 * w;
                    acc[3][jj * 4 + g] += a3 * w;
                }
            }
        }
        __syncthreads();
    }

    // epilogue: bias + LSTM cell + masked state update + running max-pool
    #pragma unroll
    for (int ni = 0; ni < 4; ++ni) {
        int nl = ng * 4 + ni;
        int n = n0 + nl;
        int len = len_s[nl];
        bool valid = (t < len);
        #pragma unroll
        for (int jj = 0; jj < 2; ++jj) {
            int j = j0 + jg * 2 + jj;
            float* rm = &enc[n * 512 + dir * 256 + j];
            if (valid) {
                float gi = acc[ni][jj * 4 + 0] + bias[          j];
                float gf = acc[ni][jj * 4 + 1] + bias[256 +     j];
                float gg = acc[ni][jj * 4 + 2] + bias[512 +     j];
                float go = acc[ni][jj * 4 + 3] + bias[768 +     j];
                float co = c[n * HH + j];
                float cn = sigm(gf) * co + sigm(gi) * tanhf(gg);
                float hn = sigm(go) * tanhf(cn);
                c[n * HH + j] = cn;
                h[n * HH + j] = hn;
                *rm = fmaxf(*rm, hn);
            } else {
                *rm = fmaxf(*rm, 0.0f);   // reference: invalid steps emit 0 into the max
            }
        }
    }
}

// ---------------- conv-level LSTM step ----------------
// grid: 16 j-tiles (32 j each), block 256. tile: 32 b x 32 j. thread: 4 b x 1 j x 4 g.
__global__ __launch_bounds__(256) void conv_step(
    const float* __restrict__ Wih_c, const float* __restrict__ Whh_c, const float* __restrict__ bc_,
    const int* __restrict__ conv_len,
    float* __restrict__ ws, int s)
{
    float* enc = ws + OFF_ENC;
    float* hc  = ws + OFF_CH;
    float* cc  = ws + OFF_CC;
    float* co  = ws + OFF_CO;

    __shared__ float As[32][17];
    __shared__ float Wsm[16][32][5];

    const int tid = threadIdx.x;
    const int j0 = blockIdx.x * 32;
    const int ng = tid & 7;     // 8 groups x 4 b
    const int jg = tid >> 3;    // 0..31, 1 j each

    float acc[4][4];
    #pragma unroll
    for (int a = 0; a < 4; ++a)
        #pragma unroll
        for (int g = 0; g < 4; ++g) acc[a][g] = 0.0f;

    for (int k0 = 0; k0 < 1024; k0 += 16) {
        #pragma unroll
        for (int i = tid; i < 512; i += 256) {
            int nl = i >> 4, kl = i & 15;
            int k = k0 + kl;
            float v;
            if (k < HC) v = enc[(s * B_DIM + nl) * HC + k];
            else        v = hc[nl * HC + (k - HC)];
            As[nl][kl] = v;
        }
        {
            int r = tid >> 1, half = tid & 1;
            int jl = r >> 2, g = r & 3;
            int row = g * 512 + j0 + jl;
            #pragma unroll
            for (int u = 0; u < 8; ++u) {
                int kl = half * 8 + u;
                int k = k0 + kl;
                float w = (k < HC) ? Wih_c[row * HC + k] : Whh_c[row * HC + (k - HC)];
                Wsm[kl][jl][g] = w;
            }
        }
        __syncthreads();
        #pragma unroll
        for (int kl = 0; kl < 16; ++kl) {
            float a0 = As[ng * 4 + 0][kl];
            float a1 = As[ng * 4 + 1][kl];
            float a2 = As[ng * 4 + 2][kl];
            float a3 = As[ng * 4 + 3][kl];
            #pragma unroll
            for (int g = 0; g < 4; ++g) {
                float w = Wsm[kl][jg][g];
                acc[0][g] += a0 * w;
                acc[1][g] += a1 * w;
                acc[2][g] += a2 * w;
                acc[3][g] += a3 * w;
            }
        }
        __syncthreads();
    }

    #pragma unroll
    for (int ni = 0; ni < 4; ++ni) {
        int b = ng * 4 + ni;
        int j = j0 + jg;
        bool valid = (s < conv_len[b]);
        float* outp = &co[(s * B_DIM + b) * HC + j];
        if (valid) {
            float gi = acc[ni][0] + bc_[           j];
            float gf = acc[ni][1] + bc_[ 512 +     j];
            float gg = acc[ni][2] + bc_[1024 +     j];
            float go = acc[ni][3] + bc_[1536 +     j];
            float cold = cc[b * HC + j];
            float cn = sigm(gf) * cold + sigm(gi) * tanhf(gg);
            float hn = sigm(go) * tanhf(cn);
            cc[b * HC + j] = cn;
            hc[b * HC + j] = hn;
            *outp = hn;
        } else {
            *outp = 0.0f;
        }
    }
}

// ---------------- final projection ----------------
// one 64-lane wave per output logit; 4 waves per block.
__global__ __launch_bounds__(256) void logits_kernel(
    const float* __restrict__ gfeat, const float* __restrict__ Wc, const float* __restrict__ bc,
    const float* __restrict__ co, float* __restrict__ out)
{
    int o = blockIdx.x * 4 + (threadIdx.x >> 6);
    int lane = threadIdx.x & 63;
    const float* row = co + o * HC;
    float sum = 0.0f;
    #pragma unroll
    for (int u = 0; u < 8; ++u) sum += row[lane + 64 * u] * Wc[lane + 64 * u];
    if (lane < F_DIM) sum += gfeat[o * F_DIM + lane] * Wc[HC + lane];
    #pragma unroll
    for (int off = 32; off > 0; off >>= 1) sum += __shfl_down(sum, off, 64);
    if (lane == 0) out[o] = sum + bc[0];
}

extern "C" void kernel_launch(void* const* d_in, const int* in_sizes, int n_in,
                              void* d_out, int out_size, void* d_ws, size_t ws_size,
                              hipStream_t stream) {
    const int*   msgs    = (const int*)  d_in[0];
    const float* gfeat   = (const float*)d_in[1];
    const int*   convlen = (const int*)  d_in[2];
    const float* E       = (const float*)d_in[3];
    const float* Wih_f   = (const float*)d_in[4];
    const float* Whh_f   = (const float*)d_in[5];
    const float* b_f     = (const float*)d_in[6];
    const float* Wih_b   = (const float*)d_in[7];
    const float* Whh_b   = (const float*)d_in[8];
    const float* b_b     = (const float*)d_in[9];
    const float* Wih_c   = (const float*)d_in[10];
    const float* Whh_c   = (const float*)d_in[11];
    const float* b_c     = (const float*)d_in[12];
    const float* Wc      = (const float*)d_in[13];
    const float* bc      = (const float*)d_in[14];
    float* out = (float*)d_out;
    float* ws  = (float*)d_ws;
    int*   mlen = (int*)(ws + OFF_LEN);

    init_ws<<<(INIT_COUNT + 255) / 256, 256, 0, stream>>>(ws);
    msg_len_kernel<<<NMSG / 256, 256, 0, stream>>>(msgs, mlen);

    for (int t = 0; t < L_DIM; ++t)
        word_step<<<dim3(32, 8, 2), 256, 0, stream>>>(msgs, mlen, E,
            Wih_f, Whh_f, b_f, Wih_b, Whh_b, b_b, ws, t);

    for (int s = 0; s < S_DIM; ++s)
        conv_step<<<16, 256, 0, stream>>>(Wih_c, Whh_c, b_c, convlen, ws, s);

    logits_kernel<<<NMSG / 4, 256, 0, stream>>>(gfeat, Wc, bc, ws + OFF_CO, out);
}

// Round 2
// 9111.390 us; speedup vs baseline: 2.2315x; 2.2315x over previous
//
#include <hip/hip_runtime.h>
#include <cmath>

#define S_DIM 64
#define B_DIM 32
#define L_DIM 64
#define NMSG  2048
#define D_DIM 300
#define HH    256        // word hidden per dir
#define HC    512        // conv hidden
#define F_DIM 16

#define KW_PAD   584     // word packed-K row stride (ushort); used K = 576 = 18*32
#define KW_TILES 18
#define KC_STRIDE 1056   // conv packed-K row stride; 33*32
#define KC_TILES  33
#define KC_LDS    1064   // conv xh LDS row stride (ushort)

// ---- ws float offsets (all 16B-aligned) ----
#define OFF_WPW   0u         // 2*1024*584 bf16 = 598016 floats
#define OFF_WPC   598016u    // 2048*1056 bf16 = 1081344 floats
#define OFF_ENCB  1679360u   // 2048*512 bf16  = 524288 floats
#define OFF_HCONV 2203648u   // 32*512 bf16    = 8192 floats
#define OFF_CCONV 2211840u   // 32*512 f32     = 16384 floats
#define OFF_CO    2228224u   // 64*32*512 f32  = 1048576 floats
#define OFF_MLEN  3276800u   // 2048 ints

typedef __attribute__((ext_vector_type(8))) short s8v;
typedef __attribute__((ext_vector_type(4))) float f4v;

#define MFMA(a,b,c) __builtin_amdgcn_mfma_f32_16x16x32_bf16((a),(b),(c),0,0,0)

__device__ __forceinline__ unsigned short f2bf(float x) {
    unsigned u = __float_as_uint(x);
    return (unsigned short)((u + 0x7FFFu + ((u >> 16) & 1u)) >> 16);
}
__device__ __forceinline__ float sigm(float x) { return 1.0f / (1.0f + __expf(-x)); }
__device__ __forceinline__ float tanh_f(float x) { return 1.0f - 2.0f / (1.0f + __expf(2.0f * x)); }

// ---------------- weight packing ----------------
__global__ __launch_bounds__(256) void pack_word(
    const float* __restrict__ Wih_f, const float* __restrict__ Whh_f, const float* __restrict__ b_f,
    const float* __restrict__ Wih_b, const float* __restrict__ Whh_b, const float* __restrict__ b_b,
    unsigned short* __restrict__ Wpw)
{
    int dir = blockIdx.x >> 10;
    int row = blockIdx.x & 1023;
    const float* Wih = dir ? Wih_b : Wih_f;
    const float* Whh = dir ? Whh_b : Whh_f;
    const float* bb  = dir ? b_b   : b_f;
    unsigned short* o = Wpw + ((size_t)dir * 1024 + row) * KW_PAD;
    for (int k = threadIdx.x; k < KW_PAD; k += 256) {
        float v = 0.0f;
        if (k < D_DIM)            v = Wih[row * D_DIM + k];
        else if (k < D_DIM + HH)  v = Whh[row * HH + (k - D_DIM)];
        else if (k == 556)        v = bb[row];
        o[k] = f2bf(v);
    }
}

__global__ __launch_bounds__(256) void pack_conv(
    const float* __restrict__ Wih_c, const float* __restrict__ Whh_c, const float* __restrict__ b_c,
    unsigned short* __restrict__ Wpc)
{
    int row = blockIdx.x;
    unsigned short* o = Wpc + (size_t)row * KC_STRIDE;
    for (int k = threadIdx.x; k < KC_STRIDE; k += 256) {
        float v = 0.0f;
        if (k < HC)            v = Wih_c[row * HC + k];
        else if (k < 2 * HC)   v = Whh_c[row * HC + (k - HC)];
        else if (k == 1024)    v = b_c[row];
        o[k] = f2bf(v);
    }
}

// ---------------- msg_len ----------------
__global__ __launch_bounds__(256) void msg_len_kernel(const int* __restrict__ msgs,
                                                      int* __restrict__ mlen) {
    int n = blockIdx.x * 256 + threadIdx.x;
    if (n >= NMSG) return;
    int cnt = 0;
    #pragma unroll 8
    for (int l = 0; l < L_DIM; ++l) cnt += (msgs[n * L_DIM + l] != 0);
    mlen[n] = max(cnt, 1);
}

// ---------------- conv state init ----------------
__global__ __launch_bounds__(256) void init_conv(float* __restrict__ ws) {
    unsigned i = blockIdx.x * 256u + threadIdx.x;
    // zero h_bf (8192 float-slots) + c (16384 floats)
    if (i < 24576u) ws[OFF_HCONV + i] = 0.0f;
}

// ---------------- persistent word-level biLSTM ----------------
// grid 128 = 64 msg-groups x 2 dirs. block 512 thr = 8 waves.
// block owns 32 sequences (one dir) for all 64 steps.
// wave: mt = wv&1 (16-seq half), q0 = (wv>>1)*4 (j-range of 64).
__global__ __launch_bounds__(512, 2) void word_lstm(
    const int* __restrict__ msgs, const int* __restrict__ mlen,
    const float* __restrict__ E,
    const unsigned short* __restrict__ Wpw,
    unsigned short* __restrict__ enc_bf)
{
    __shared__ unsigned short xh[32][KW_PAD];
    __shared__ int tok_s[32][64];
    __shared__ int len_s[32];

    const int mg  = blockIdx.x >> 1;
    const int dir = blockIdx.x & 1;
    const int tid = threadIdx.x;
    const int lane = tid & 63;
    const int wv   = tid >> 6;
    const int l15  = lane & 15;
    const int kg   = lane >> 4;
    const int mt   = wv & 1;
    const int q0   = (wv >> 1) << 2;

    // prefetch tokens + len; init xh (h-region zero, bias slot, pads)
    for (int i = tid; i < 32 * 64; i += 512) {
        int sq = i >> 6, l = i & 63;
        tok_s[sq][l] = msgs[(mg * 32 + sq) * L_DIM + l];
    }
    if (tid < 32) len_s[tid] = mlen[mg * 32 + tid];
    for (int i = tid; i < 32 * KW_PAD; i += 512) {
        int sq = i / KW_PAD, k = i - sq * KW_PAD;
        xh[sq][k] = (k == 556) ? (unsigned short)0x3F80 : (unsigned short)0;
    }
    __syncthreads();

    const unsigned short* Wb = Wpw + (size_t)dir * 1024 * KW_PAD;
    const s8v* bp[16];
    #pragma unroll
    for (int q = 0; q < 4; ++q)
        #pragma unroll
        for (int g = 0; g < 4; ++g)
            bp[q * 4 + g] = (const s8v*)(Wb + (size_t)(g * 256 + (q0 + q) * 16 + l15) * KW_PAD) + kg;

    const s8v* ap = (const s8v*)(&xh[mt * 16 + l15][0]) + kg;

    float c[4][4], rm[4][4], hval[4][4];
    #pragma unroll
    for (int q = 0; q < 4; ++q)
        #pragma unroll
        for (int r = 0; r < 4; ++r) { c[q][r] = 0.0f; rm[q][r] = -INFINITY; }

    int lens[4];
    #pragma unroll
    for (int r = 0; r < 4; ++r) lens[r] = len_s[mt * 16 + kg * 4 + r];

    for (int t = 0; t < L_DIM; ++t) {
        // ---- stage x_t into xh[.][0..299] ----
        {
            int sq = tid >> 4, sub = tid & 15;
            int len = len_s[sq];
            int tt = dir ? (len - 1 - t) : t;
            if (tt < 0) tt = 0;
            const float* er = E + (size_t)tok_s[sq][tt] * D_DIM;
            #pragma unroll
            for (int u = 0; u < 19; ++u) {
                int d = sub + (u << 4);
                if (d < D_DIM) xh[sq][d] = f2bf(er[d]);
            }
        }
        __syncthreads();   // xh (x staged; h from prev step) ready

        // ---- gates = [x|h|1] @ Wpk^T : M=16(seqs of mt), N=256(j-range x 4 gates), K=576 ----
        f4v acc[16];
        const f4v zf = {0.0f, 0.0f, 0.0f, 0.0f};
        #pragma unroll
        for (int n = 0; n < 16; ++n) acc[n] = zf;

        for (int kt = 0; kt < KW_TILES; ++kt) {
            s8v a = ap[kt * 4];
            #pragma unroll
            for (int n = 0; n < 16; ++n)
                acc[n] = MFMA(a, bp[n][kt * 4], acc[n]);
        }

        // ---- cell update (all in registers) ----
        #pragma unroll
        for (int q = 0; q < 4; ++q) {
            #pragma unroll
            for (int r = 0; r < 4; ++r) {
                float g_i = acc[q * 4 + 0][r];
                float g_f = acc[q * 4 + 1][r];
                float g_c = acc[q * 4 + 2][r];
                float g_o = acc[q * 4 + 3][r];
                float cn = sigm(g_f) * c[q][r] + sigm(g_i) * tanh_f(g_c);
                float hn = sigm(g_o) * tanh_f(cn);
                hval[q][r] = hn;
                if (t < lens[r]) { c[q][r] = cn; rm[q][r] = fmaxf(rm[q][r], hn); }
                else             rm[q][r] = fmaxf(rm[q][r], 0.0f);
            }
        }
        __syncthreads();   // all xh reads done -> safe to overwrite h-region
        #pragma unroll
        for (int q = 0; q < 4; ++q)
            #pragma unroll
            for (int r = 0; r < 4; ++r)
                if (t < lens[r])
                    xh[mt * 16 + kg * 4 + r][D_DIM + (q0 + q) * 16 + l15] = f2bf(hval[q][r]);
    }

    // ---- write enc (max-pool result), bf16 ----
    #pragma unroll
    for (int q = 0; q < 4; ++q)
        #pragma unroll
        for (int r = 0; r < 4; ++r) {
            int n = mg * 32 + mt * 16 + kg * 4 + r;
            int j = (q0 + q) * 16 + l15;
            enc_bf[(size_t)n * HC + dir * HH + j] = f2bf(rm[q][r]);
        }
}

// ---------------- conv-level LSTM step (MFMA) ----------------
// grid 32 blocks (16-j tiles), 256 thr = 4 waves: (mt = wv&1, gate-pair = wv>>1)
__global__ __launch_bounds__(256) void conv_step(
    const unsigned short* __restrict__ Wpc,
    const unsigned short* __restrict__ enc_bf,
    const int* __restrict__ conv_len,
    unsigned short* __restrict__ h_bf,
    float* __restrict__ c_ws,
    float* __restrict__ co,
    int s)
{
    __shared__ unsigned short xh[32][KC_LDS];
    __shared__ float gbuf[4][32][16];

    const int tid = threadIdx.x;
    const int jb = blockIdx.x;
    const int lane = tid & 63, wv = tid >> 6;
    const int l15 = lane & 15, kg = lane >> 4;
    const int mt = wv & 1, gp = wv >> 1;

    // stage xh: [b][0..511]=enc_s, [512..1023]=h, [1024]=1, pad=0
    {
        int b = tid >> 3, sub = tid & 7;
        const uint4* esrc = (const uint4*)(enc_bf + ((size_t)(s * B_DIM + b)) * HC);
        const uint4* hsrc = (const uint4*)(h_bf + (size_t)b * HC);
        uint4* dst  = (uint4*)(&xh[b][0]);
        uint4* dst2 = (uint4*)(&xh[b][512]);
        #pragma unroll
        for (int u = 0; u < 8; ++u) dst[sub + 8 * u]  = esrc[sub + 8 * u];
        #pragma unroll
        for (int u = 0; u < 8; ++u) dst2[sub + 8 * u] = hsrc[sub + 8 * u];
        if (sub == 0) {
            xh[b][1024] = (unsigned short)0x3F80;
            for (int k = 1025; k < KC_LDS; ++k) xh[b][k] = 0;
        }
    }
    __syncthreads();

    const s8v* ap  = (const s8v*)(&xh[mt * 16 + l15][0]) + kg;
    const s8v* bp0 = (const s8v*)(Wpc + (size_t)((gp * 2 + 0) * HC + jb * 16 + l15) * KC_STRIDE) + kg;
    const s8v* bp1 = (const s8v*)(Wpc + (size_t)((gp * 2 + 1) * HC + jb * 16 + l15) * KC_STRIDE) + kg;

    const f4v zf = {0.0f, 0.0f, 0.0f, 0.0f};
    f4v a0 = zf, a1 = zf;
    for (int kt = 0; kt < KC_TILES; ++kt) {
        s8v a = ap[kt * 4];
        a0 = MFMA(a, bp0[kt * 4], a0);
        a1 = MFMA(a, bp1[kt * 4], a1);
    }
    #pragma unroll
    for (int r = 0; r < 4; ++r) {
        int m = mt * 16 + kg * 4 + r;
        gbuf[gp * 2 + 0][m][l15] = a0[r];
        gbuf[gp * 2 + 1][m][l15] = a1[r];
    }
    __syncthreads();

    #pragma unroll
    for (int u = 0; u < 2; ++u) {
        int cell = tid + 256 * u;
        int b = cell >> 4, jj = cell & 15;
        int j = jb * 16 + jj;
        bool valid = s < conv_len[b];
        float g_i = gbuf[0][b][jj], g_f = gbuf[1][b][jj];
        float g_c = gbuf[2][b][jj], g_o = gbuf[3][b][jj];
        float cold = c_ws[b * HC + j];
        float cn = sigm(g_f) * cold + sigm(g_i) * tanh_f(g_c);
        float hn = sigm(g_o) * tanh_f(cn);
        float outv = 0.0f;
        if (valid) {
            c_ws[b * HC + j] = cn;
            h_bf[b * HC + j] = f2bf(hn);
            outv = hn;
        }
        co[((size_t)s * B_DIM + b) * HC + j] = outv;
    }
}

// ---------------- final projection ----------------
__global__ __launch_bounds__(256) void logits_kernel(
    const float* __restrict__ gfeat, const float* __restrict__ Wc, const float* __restrict__ bc,
    const float* __restrict__ co, float* __restrict__ out)
{
    int o = blockIdx.x * 4 + (threadIdx.x >> 6);
    int lane = threadIdx.x & 63;
    const float* row = co + (size_t)o * HC;
    float sum = 0.0f;
    #pragma unroll
    for (int u = 0; u < 8; ++u) sum += row[lane + 64 * u] * Wc[lane + 64 * u];
    if (lane < F_DIM) sum += gfeat[o * F_DIM + lane] * Wc[HC + lane];
    #pragma unroll
    for (int off = 32; off > 0; off >>= 1) sum += __shfl_down(sum, off, 64);
    if (lane == 0) out[o] = sum + bc[0];
}

extern "C" void kernel_launch(void* const* d_in, const int* in_sizes, int n_in,
                              void* d_out, int out_size, void* d_ws, size_t ws_size,
                              hipStream_t stream) {
    const int*   msgs    = (const int*)  d_in[0];
    const float* gfeat   = (const float*)d_in[1];
    const int*   convlen = (const int*)  d_in[2];
    const float* E       = (const float*)d_in[3];
    const float* Wih_f   = (const float*)d_in[4];
    const float* Whh_f   = (const float*)d_in[5];
    const float* b_f     = (const float*)d_in[6];
    const float* Wih_b   = (const float*)d_in[7];
    const float* Whh_b   = (const float*)d_in[8];
    const float* b_b     = (const float*)d_in[9];
    const float* Wih_c   = (const float*)d_in[10];
    const float* Whh_c   = (const float*)d_in[11];
    const float* b_c     = (const float*)d_in[12];
    const float* Wc      = (const float*)d_in[13];
    const float* bc      = (const float*)d_in[14];
    float* out = (float*)d_out;
    float* ws  = (float*)d_ws;

    unsigned short* Wpw    = (unsigned short*)(ws + OFF_WPW);
    unsigned short* Wpc    = (unsigned short*)(ws + OFF_WPC);
    unsigned short* enc_bf = (unsigned short*)(ws + OFF_ENCB);
    unsigned short* h_bf   = (unsigned short*)(ws + OFF_HCONV);
    float*          c_ws   = ws + OFF_CCONV;
    float*          co     = ws + OFF_CO;
    int*            mlen   = (int*)(ws + OFF_MLEN);

    pack_word<<<2048, 256, 0, stream>>>(Wih_f, Whh_f, b_f, Wih_b, Whh_b, b_b, Wpw);
    pack_conv<<<2048, 256, 0, stream>>>(Wih_c, Whh_c, b_c, Wpc);
    msg_len_kernel<<<NMSG / 256, 256, 0, stream>>>(msgs, mlen);
    init_conv<<<96, 256, 0, stream>>>(ws);

    word_lstm<<<128, 512, 0, stream>>>(msgs, mlen, E, Wpw, enc_bf);

    for (int s = 0; s < S_DIM; ++s)
        conv_step<<<32, 256, 0, stream>>>(Wpc, enc_bf, convlen, h_bf, c_ws, co, s);

    logits_kernel<<<NMSG / 4, 256, 0, stream>>>(gfeat, Wc, bc, co, out);
}

// Round 3
// 2382.452 us; speedup vs baseline: 8.5340x; 3.8244x over previous
//
#include <hip/hip_runtime.h>
#include <cmath>

#define S_DIM 64
#define B_DIM 32
#define L_DIM 64
#define NMSG  2048
#define D_DIM 300
#define HH    256
#define HC    512
#define F_DIM 16
#define VOCAB 32000

// conv packing (unchanged from R2)
#define KC_STRIDE 1056
#define KC_TILES  33
#define KC_LDS    1064

// ---- ws float offsets ----
#define OFF_XGV   0u          // 2*32000*1024 bf16 = 32768000 floats
#define OFF_WHH   32768000u   // 2*1024*256 bf16 frag-packed = 262144 floats
#define OFF_WPC   33030144u   // 2048*1056 bf16 = 1081344 floats
#define OFF_ENCB  34111488u   // 2048*512 bf16 = 524288 floats
#define OFF_HCONV 34635776u   // 32*512 bf16 = 8192 floats
#define OFF_CCONV 34643968u   // 32*512 f32 = 16384 floats
#define OFF_CO    34660352u   // 64*32*512 f32 = 1048576 floats
#define OFF_MLEN  35708928u   // 2048 ints

typedef __attribute__((ext_vector_type(8))) short s8v;
typedef __attribute__((ext_vector_type(4))) float f4v;
#define MFMA(a,b,c) __builtin_amdgcn_mfma_f32_16x16x32_bf16((a),(b),(c),0,0,0)

__device__ __forceinline__ unsigned short f2bf(float x) {
    unsigned u = __float_as_uint(x);
    return (unsigned short)((u + 0x7FFFu + ((u >> 16) & 1u)) >> 16);
}
__device__ __forceinline__ float bf2f(unsigned short u) {
    return __uint_as_float(((unsigned)u) << 16);
}
__device__ __forceinline__ float sigm(float x) { return 1.0f / (1.0f + __expf(-x)); }
__device__ __forceinline__ float tanh_f(float x) { return 1.0f - 2.0f / (1.0f + __expf(2.0f * x)); }

// ---------------- pack Whh fragment-ordered ----------------
// layout: [dir][nt(64)][kt(8)][lane(64)][8]  (ushort)
__global__ __launch_bounds__(256) void pack_whh(
    const float* __restrict__ Whh_f, const float* __restrict__ Whh_b,
    unsigned short* __restrict__ Wp)
{
    int nt = blockIdx.x, dir = blockIdx.y;
    const float* W = dir ? Whh_b : Whh_f;
    int tid = threadIdx.x, lane = tid & 63, ktq = tid >> 6;
    int n = nt * 16 + (lane & 15);
    #pragma unroll
    for (int pass = 0; pass < 2; ++pass) {
        int kt = ktq + pass * 4;
        int k0 = kt * 32 + (lane >> 4) * 8;
        unsigned short tmp[8];
        #pragma unroll
        for (int u = 0; u < 8; ++u) tmp[u] = f2bf(W[(size_t)n * HH + k0 + u]);
        unsigned short* dst = Wp + (size_t)dir * 524288 + ((size_t)(nt * 8 + kt)) * 1024 + lane * 8;
        *(uint4*)dst = *(uint4*)tmp;
    }
}

// ---------------- pack conv weights (R2) ----------------
__global__ __launch_bounds__(256) void pack_conv(
    const float* __restrict__ Wih_c, const float* __restrict__ Whh_c, const float* __restrict__ b_c,
    unsigned short* __restrict__ Wpc)
{
    int row = blockIdx.x;
    unsigned short* o = Wpc + (size_t)row * KC_STRIDE;
    for (int k = threadIdx.x; k < KC_STRIDE; k += 256) {
        float v = 0.0f;
        if (k < HC)            v = Wih_c[row * HC + k];
        else if (k < 2 * HC)   v = Whh_c[row * HC + (k - HC)];
        else if (k == 1024)    v = b_c[row];
        o[k] = f2bf(v);
    }
}

// ---------------- msg_len ----------------
__global__ __launch_bounds__(256) void msg_len_kernel(const int* __restrict__ msgs,
                                                      int* __restrict__ mlen) {
    int n = blockIdx.x * 256 + threadIdx.x;
    if (n >= NMSG) return;
    int cnt = 0;
    #pragma unroll 8
    for (int l = 0; l < L_DIM; ++l) cnt += (msgs[n * L_DIM + l] != 0);
    mlen[n] = max(cnt, 1);
}

__global__ __launch_bounds__(256) void init_conv(float* __restrict__ ws) {
    unsigned i = blockIdx.x * 256u + threadIdx.x;
    if (i < 24576u) ws[OFF_HCONV + i] = 0.0f;
}

// ---------------- xg_vocab GEMM: E(32000x300) @ [Wih_f|Wih_b]^T + b ----------------
// grid (1000 wordtiles, 8 ntiles-of-256), block 256 = 4 waves; wave: 32 words x 64 n.
#define EROW 328
__global__ __launch_bounds__(256) void xg_gemm(
    const float* __restrict__ E,
    const float* __restrict__ Wih_f, const float* __restrict__ b_f,
    const float* __restrict__ Wih_b, const float* __restrict__ b_b,
    unsigned short* __restrict__ xgv)
{
    __shared__ __align__(16) unsigned short e_lds[32 * EROW];
    const int w0 = blockIdx.x * 32;
    const int n0 = blockIdx.y * 256;
    const int dirb = n0 >> 10;
    const float* W = dirb ? Wih_b : Wih_f;
    const float* bias = dirb ? b_b : b_f;
    const int nb = n0 & 1023;

    const int tid = threadIdx.x, lane = tid & 63, wv = tid >> 6;
    const int l15 = lane & 15, kg = lane >> 4;

    for (int i = tid; i < 32 * 320; i += 256) {
        int r = i / 320, k = i - r * 320;
        float v = (k < D_DIM) ? E[(size_t)(w0 + r) * D_DIM + k] : 0.0f;
        e_lds[r * EROW + k] = f2bf(v);
    }
    __syncthreads();

    const f4v zf = {0.0f, 0.0f, 0.0f, 0.0f};
    f4v acc[2][4];
    #pragma unroll
    for (int m = 0; m < 2; ++m)
        #pragma unroll
        for (int q = 0; q < 4; ++q) acc[m][q] = zf;

    for (int kt = 0; kt < 10; ++kt) {
        s8v a0 = *(const s8v*)&e_lds[l15 * EROW + kt * 32 + kg * 8];
        s8v a1 = *(const s8v*)&e_lds[(16 + l15) * EROW + kt * 32 + kg * 8];
        #pragma unroll
        for (int q = 0; q < 4; ++q) {
            int row = nb + (wv * 4 + q) * 16 + l15;
            int k0 = kt * 32 + kg * 8;
            s8v bfr;
            if (kt < 9) {
                const float* wp = W + (size_t)row * D_DIM + k0;
                #pragma unroll
                for (int u = 0; u < 8; ++u) bfr[u] = (short)f2bf(wp[u]);
            } else {
                #pragma unroll
                for (int u = 0; u < 8; ++u) {
                    int k = k0 + u;
                    float v = (k < D_DIM) ? W[(size_t)row * D_DIM + k] : 0.0f;
                    bfr[u] = (short)f2bf(v);
                }
            }
            acc[0][q] = MFMA(a0, bfr, acc[0][q]);
            acc[1][q] = MFMA(a1, bfr, acc[1][q]);
        }
    }

    #pragma unroll
    for (int m = 0; m < 2; ++m)
        #pragma unroll
        for (int q = 0; q < 4; ++q) {
            int row = nb + (wv * 4 + q) * 16 + l15;
            float bv = bias[row];
            #pragma unroll
            for (int r = 0; r < 4; ++r) {
                int word = w0 + m * 16 + kg * 4 + r;
                xgv[((size_t)dirb * VOCAB + word) * 1024 + row] = f2bf(acc[m][q][r] + bv);
            }
        }
}

// ---------------- persistent word biLSTM, K=256 recurrence ----------------
// grid 128 (64 mg x 2 dir), block 512 = 8 waves. wave wv owns j in [wv*32,(wv+1)*32), all gates.
#define HROW  264
#define XGROW 520
__global__ __launch_bounds__(512) void word_lstm(
    const int* __restrict__ msgs, const int* __restrict__ mlen,
    const unsigned short* __restrict__ xgv,
    const unsigned short* __restrict__ whh,
    unsigned short* __restrict__ enc_bf)
{
    __shared__ __align__(16) unsigned short h_lds[32 * HROW];
    __shared__ __align__(16) unsigned short xg_buf[32 * XGROW];
    __shared__ int tok_s[32 * 64];
    __shared__ int len_s[32];

    const int mg = blockIdx.x >> 1, dir = blockIdx.x & 1;
    const int tid = threadIdx.x, lane = tid & 63, wv = tid >> 6;
    const int l15 = lane & 15, kg = lane >> 4;

    for (int i = tid; i < 32 * 64; i += 512) tok_s[i] = msgs[mg * 32 * 64 + i];
    if (tid < 32) len_s[tid] = mlen[mg * 32 + tid];
    for (int i = tid; i < 32 * HROW; i += 512) h_lds[i] = 0;
    __syncthreads();

    // staging role: thread (sp, sc) copies 64B of xg row sp per half
    const int sp = tid >> 4, sc = tid & 15;
    const int splen = len_s[sp];
    const unsigned short* xrow_base = xgv + (size_t)dir * VOCAB * 1024;
    uint4* xgb4 = (uint4*)xg_buf;       // row stride 65 uint4

    const unsigned short* wb = whh + (size_t)dir * 524288;

    uint4 R0[4], R1[4];
    {
        int tt = dir ? (splen - 1) : 0;
        if (tt < 0 || tt > 63) tt = 0;
        const uint4* src = (const uint4*)(xrow_base + (size_t)tok_s[sp * 64 + tt] * 1024);
        #pragma unroll
        for (int u = 0; u < 4; ++u) R0[u] = src[sc * 4 + u];
        #pragma unroll
        for (int u = 0; u < 4; ++u) R1[u] = src[64 + sc * 4 + u];
    }

    const f4v zf = {0.0f, 0.0f, 0.0f, 0.0f};
    float c_st[2][2][4], rm[2][2][4], hval[2][2][4];
    #pragma unroll
    for (int m = 0; m < 2; ++m)
        #pragma unroll
        for (int q = 0; q < 2; ++q)
            #pragma unroll
            for (int r = 0; r < 4; ++r) { c_st[m][q][r] = 0.0f; rm[m][q][r] = -INFINITY; }

    int lens[2][4];
    #pragma unroll
    for (int m = 0; m < 2; ++m)
        #pragma unroll
        for (int r = 0; r < 4; ++r) lens[m][r] = len_s[m * 16 + kg * 4 + r];

    for (int t = 0; t < L_DIM; ++t) {
        f4v acc[16];

        // half 0 (gates 0,1)
        #pragma unroll
        for (int u = 0; u < 4; ++u) xgb4[sp * 65 + sc * 4 + u] = R0[u];
        __syncthreads();
        #pragma unroll
        for (int m = 0; m < 2; ++m)
            #pragma unroll
            for (int q = 0; q < 2; ++q)
                #pragma unroll
                for (int gg = 0; gg < 2; ++gg) {
                    int col = gg * 256 + (wv * 2 + q) * 16 + l15;
                    f4v v;
                    #pragma unroll
                    for (int r = 0; r < 4; ++r)
                        v[r] = bf2f(xg_buf[(m * 16 + kg * 4 + r) * XGROW + col]);
                    acc[m * 8 + q * 4 + gg] = v;
                }
        __syncthreads();

        // half 1 (gates 2,3)
        #pragma unroll
        for (int u = 0; u < 4; ++u) xgb4[sp * 65 + sc * 4 + u] = R1[u];
        __syncthreads();
        #pragma unroll
        for (int m = 0; m < 2; ++m)
            #pragma unroll
            for (int q = 0; q < 2; ++q)
                #pragma unroll
                for (int gg = 0; gg < 2; ++gg) {
                    int col = gg * 256 + (wv * 2 + q) * 16 + l15;
                    f4v v;
                    #pragma unroll
                    for (int r = 0; r < 4; ++r)
                        v[r] = bf2f(xg_buf[(m * 16 + kg * 4 + r) * XGROW + col]);
                    acc[m * 8 + q * 4 + 2 + gg] = v;
                }

        // prefetch next step's xg row
        {
            int tn = t + 1;
            int tt = dir ? (splen - 1 - tn) : tn;
            if (tt < 0 || tt > 63) tt = 0;
            const uint4* src = (const uint4*)(xrow_base + (size_t)tok_s[sp * 64 + tt] * 1024);
            #pragma unroll
            for (int u = 0; u < 4; ++u) R0[u] = src[sc * 4 + u];
            #pragma unroll
            for (int u = 0; u < 4; ++u) R1[u] = src[64 + sc * 4 + u];
        }

        // K-loop: gates += h @ Whh^T  (K = 256 = 8 kt)
        for (int kt = 0; kt < 8; ++kt) {
            s8v a0 = *(const s8v*)&h_lds[l15 * HROW + kt * 32 + kg * 8];
            s8v a1 = *(const s8v*)&h_lds[(16 + l15) * HROW + kt * 32 + kg * 8];
            #pragma unroll
            for (int g = 0; g < 4; ++g)
                #pragma unroll
                for (int q = 0; q < 2; ++q) {
                    int nt = g * 16 + wv * 2 + q;
                    s8v b = *(const s8v*)(wb + ((size_t)(nt * 8 + kt)) * 1024 + lane * 8);
                    acc[0 * 8 + q * 4 + g] = MFMA(a0, b, acc[0 * 8 + q * 4 + g]);
                    acc[1 * 8 + q * 4 + g] = MFMA(a1, b, acc[1 * 8 + q * 4 + g]);
                }
        }

        // cell update
        #pragma unroll
        for (int m = 0; m < 2; ++m)
            #pragma unroll
            for (int q = 0; q < 2; ++q)
                #pragma unroll
                for (int r = 0; r < 4; ++r) {
                    float gi = acc[m * 8 + q * 4 + 0][r];
                    float gf = acc[m * 8 + q * 4 + 1][r];
                    float gc = acc[m * 8 + q * 4 + 2][r];
                    float go = acc[m * 8 + q * 4 + 3][r];
                    float cn = sigm(gf) * c_st[m][q][r] + sigm(gi) * tanh_f(gc);
                    float hn = sigm(go) * tanh_f(cn);
                    hval[m][q][r] = hn;
                    if (t < lens[m][r]) { c_st[m][q][r] = cn; rm[m][q][r] = fmaxf(rm[m][q][r], hn); }
                    else                 rm[m][q][r] = fmaxf(rm[m][q][r], 0.0f);
                }
        __syncthreads();   // all h_lds reads done
        #pragma unroll
        for (int m = 0; m < 2; ++m)
            #pragma unroll
            for (int q = 0; q < 2; ++q)
                #pragma unroll
                for (int r = 0; r < 4; ++r)
                    if (t < lens[m][r])
                        h_lds[(m * 16 + kg * 4 + r) * HROW + (wv * 2 + q) * 16 + l15] = f2bf(hval[m][q][r]);
        __syncthreads();   // h writes visible
    }

    #pragma unroll
    for (int m = 0; m < 2; ++m)
        #pragma unroll
        for (int q = 0; q < 2; ++q)
            #pragma unroll
            for (int r = 0; r < 4; ++r) {
                int n = mg * 32 + m * 16 + kg * 4 + r;
                int j = (wv * 2 + q) * 16 + l15;
                enc_bf[(size_t)n * HC + dir * HH + j] = f2bf(rm[m][q][r]);
            }
}

// ---------------- conv-level LSTM step (R2, unchanged) ----------------
__global__ __launch_bounds__(256) void conv_step(
    const unsigned short* __restrict__ Wpc,
    const unsigned short* __restrict__ enc_bf,
    const int* __restrict__ conv_len,
    unsigned short* __restrict__ h_bf,
    float* __restrict__ c_ws,
    float* __restrict__ co,
    int s)
{
    __shared__ unsigned short xh[32][KC_LDS];
    __shared__ float gbuf[4][32][16];

    const int tid = threadIdx.x;
    const int jb = blockIdx.x;
    const int lane = tid & 63, wv = tid >> 6;
    const int l15 = lane & 15, kg = lane >> 4;
    const int mt = wv & 1, gp = wv >> 1;

    {
        int b = tid >> 3, sub = tid & 7;
        const uint4* esrc = (const uint4*)(enc_bf + ((size_t)(s * B_DIM + b)) * HC);
        const uint4* hsrc = (const uint4*)(h_bf + (size_t)b * HC);
        uint4* dst  = (uint4*)(&xh[b][0]);
        uint4* dst2 = (uint4*)(&xh[b][512]);
        #pragma unroll
        for (int u = 0; u < 8; ++u) dst[sub + 8 * u]  = esrc[sub + 8 * u];
        #pragma unroll
        for (int u = 0; u < 8; ++u) dst2[sub + 8 * u] = hsrc[sub + 8 * u];
        if (sub == 0) {
            xh[b][1024] = (unsigned short)0x3F80;
            for (int k = 1025; k < KC_LDS; ++k) xh[b][k] = 0;
        }
    }
    __syncthreads();

    const s8v* ap  = (const s8v*)(&xh[mt * 16 + l15][0]) + kg;
    const s8v* bp0 = (const s8v*)(Wpc + (size_t)((gp * 2 + 0) * HC + jb * 16 + l15) * KC_STRIDE) + kg;
    const s8v* bp1 = (const s8v*)(Wpc + (size_t)((gp * 2 + 1) * HC + jb * 16 + l15) * KC_STRIDE) + kg;

    const f4v zf = {0.0f, 0.0f, 0.0f, 0.0f};
    f4v a0 = zf, a1 = zf;
    for (int kt = 0; kt < KC_TILES; ++kt) {
        s8v a = ap[kt * 4];
        a0 = MFMA(a, bp0[kt * 4], a0);
        a1 = MFMA(a, bp1[kt * 4], a1);
    }
    #pragma unroll
    for (int r = 0; r < 4; ++r) {
        int m = mt * 16 + kg * 4 + r;
        gbuf[gp * 2 + 0][m][l15] = a0[r];
        gbuf[gp * 2 + 1][m][l15] = a1[r];
    }
    __syncthreads();

    #pragma unroll
    for (int u = 0; u < 2; ++u) {
        int cell = tid + 256 * u;
        int b = cell >> 4, jj = cell & 15;
        int j = jb * 16 + jj;
        bool valid = s < conv_len[b];
        float g_i = gbuf[0][b][jj], g_f = gbuf[1][b][jj];
        float g_c = gbuf[2][b][jj], g_o = gbuf[3][b][jj];
        float cold = c_ws[b * HC + j];
        float cn = sigm(g_f) * cold + sigm(g_i) * tanh_f(g_c);
        float hn = sigm(g_o) * tanh_f(cn);
        float outv = 0.0f;
        if (valid) {
            c_ws[b * HC + j] = cn;
            h_bf[b * HC + j] = f2bf(hn);
            outv = hn;
        }
        co[((size_t)s * B_DIM + b) * HC + j] = outv;
    }
}

// ---------------- final projection ----------------
__global__ __launch_bounds__(256) void logits_kernel(
    const float* __restrict__ gfeat, const float* __restrict__ Wc, const float* __restrict__ bc,
    const float* __restrict__ co, float* __restrict__ out)
{
    int o = blockIdx.x * 4 + (threadIdx.x >> 6);
    int lane = threadIdx.x & 63;
    const float* row = co + (size_t)o * HC;
    float sum = 0.0f;
    #pragma unroll
    for (int u = 0; u < 8; ++u) sum += row[lane + 64 * u] * Wc[lane + 64 * u];
    if (lane < F_DIM) sum += gfeat[o * F_DIM + lane] * Wc[HC + lane];
    #pragma unroll
    for (int off = 32; off > 0; off >>= 1) sum += __shfl_down(sum, off, 64);
    if (lane == 0) out[o] = sum + bc[0];
}

extern "C" void kernel_launch(void* const* d_in, const int* in_sizes, int n_in,
                              void* d_out, int out_size, void* d_ws, size_t ws_size,
                              hipStream_t stream) {
    const int*   msgs    = (const int*)  d_in[0];
    const float* gfeat   = (const float*)d_in[1];
    const int*   convlen = (const int*)  d_in[2];
    const float* E       = (const float*)d_in[3];
    const float* Wih_f   = (const float*)d_in[4];
    const float* Whh_f   = (const float*)d_in[5];
    const float* b_f     = (const float*)d_in[6];
    const float* Wih_b   = (const float*)d_in[7];
    const float* Whh_b   = (const float*)d_in[8];
    const float* b_b     = (const float*)d_in[9];
    const float* Wih_c   = (const float*)d_in[10];
    const float* Whh_c   = (const float*)d_in[11];
    const float* b_c     = (const float*)d_in[12];
    const float* Wc      = (const float*)d_in[13];
    const float* bc      = (const float*)d_in[14];
    float* out = (float*)d_out;
    float* ws  = (float*)d_ws;

    unsigned short* xgv    = (unsigned short*)(ws + OFF_XGV);
    unsigned short* whh    = (unsigned short*)(ws + OFF_WHH);
    unsigned short* Wpc    = (unsigned short*)(ws + OFF_WPC);
    unsigned short* enc_bf = (unsigned short*)(ws + OFF_ENCB);
    unsigned short* h_bf   = (unsigned short*)(ws + OFF_HCONV);
    float*          c_ws   = ws + OFF_CCONV;
    float*          co     = ws + OFF_CO;
    int*            mlen   = (int*)(ws + OFF_MLEN);

    pack_whh<<<dim3(64, 2), 256, 0, stream>>>(Whh_f, Whh_b, whh);
    pack_conv<<<2048, 256, 0, stream>>>(Wih_c, Whh_c, b_c, Wpc);
    msg_len_kernel<<<NMSG / 256, 256, 0, stream>>>(msgs, mlen);
    init_conv<<<96, 256, 0, stream>>>(ws);
    xg_gemm<<<dim3(1000, 8), 256, 0, stream>>>(E, Wih_f, b_f, Wih_b, b_b, xgv);

    word_lstm<<<128, 512, 0, stream>>>(msgs, mlen, xgv, whh, enc_bf);

    for (int s = 0; s < S_DIM; ++s)
        conv_step<<<32, 256, 0, stream>>>(Wpc, enc_bf, convlen, h_bf, c_ws, co, s);

    logits_kernel<<<NMSG / 4, 256, 0, stream>>>(gfeat, Wc, bc, co, out);
}

// Round 4
// 1508.907 us; speedup vs baseline: 13.4746x; 1.5789x over previous
//
#include <hip/hip_runtime.h>
#include <cmath>

#define S_DIM 64
#define B_DIM 32
#define L_DIM 64
#define NMSG  2048
#define D_DIM 300
#define HH    256
#define HC    512
#define F_DIM 16
#define VOCAB 32000

#define KC_STRIDE 1056
#define KC_TILES  33
#define KC_LDS    1064

// ---- ws float offsets ----
#define OFF_XGV   0u          // 2*32000*1024 bf16 = 32768000 floats
#define OFF_WHH   32768000u   // 2*64*8*512 u16 tight-packed = 262144 floats
#define OFF_WPI   33030144u   // 2*64*10*512 u16 = 327680 floats
#define OFF_WPC   33357824u   // 2048*1056 u16 = 1081344 floats
#define OFF_ENCB  34439168u   // 2048*512 u16 = 524288 floats
#define OFF_HCONV 34963456u   // 32*512 u16 = 8192 floats
#define OFF_CCONV 34971648u   // 32*512 f32 = 16384 floats
#define OFF_CO    34988032u   // 64*32*512 f32 = 1048576 floats
#define OFF_MLEN  36036608u   // 2048 ints

typedef __attribute__((ext_vector_type(8))) short s8v;
typedef __attribute__((ext_vector_type(4))) float f4v;
#define MFMA(a,b,c) __builtin_amdgcn_mfma_f32_16x16x32_bf16((a),(b),(c),0,0,0)

__device__ __forceinline__ unsigned short f2bf(float x) {
    unsigned u = __float_as_uint(x);
    return (unsigned short)((u + 0x7FFFu + ((u >> 16) & 1u)) >> 16);
}
__device__ __forceinline__ float bf2f(unsigned short u) {
    return __uint_as_float(((unsigned)u) << 16);
}
__device__ __forceinline__ float sigm(float x) { return 1.0f / (1.0f + __expf(-x)); }
__device__ __forceinline__ float tanh_f(float x) { return 1.0f - 2.0f / (1.0f + __expf(2.0f * x)); }

// async global->LDS, 16B per lane; LDS dest = uniform base + lane*16
__device__ __forceinline__ void gload16(const unsigned short* g, unsigned short* l) {
    __builtin_amdgcn_global_load_lds(
        (const __attribute__((address_space(1))) unsigned int*)g,
        (__attribute__((address_space(3))) unsigned int*)l, 16, 0, 0);
}

// ---------------- pack Whh fragment-ordered (tight, stride 512) ----------------
// layout: [dir][(nt*8+kt)*512 + lane*8]
__global__ __launch_bounds__(256) void pack_whh(
    const float* __restrict__ Whh_f, const float* __restrict__ Whh_b,
    unsigned short* __restrict__ Wp)
{
    int nt = blockIdx.x, dir = blockIdx.y;
    const float* W = dir ? Whh_b : Whh_f;
    int tid = threadIdx.x, lane = tid & 63, ktq = tid >> 6;
    int n = nt * 16 + (lane & 15);
    int kb = (lane >> 4) * 8;
    #pragma unroll
    for (int pass = 0; pass < 2; ++pass) {
        int kt = ktq + pass * 4;
        int k0 = kt * 32 + kb;
        unsigned short tmp[8];
        #pragma unroll
        for (int u = 0; u < 8; ++u) tmp[u] = f2bf(W[(size_t)n * HH + k0 + u]);
        *(uint4*)(Wp + (size_t)dir * 262144 + ((size_t)(nt * 8 + kt)) * 512 + lane * 8) = *(uint4*)tmp;
    }
}

// ---------------- pack Wih fragment-ordered (K padded 300->320) ----------------
// layout: [dir][(nt*10+kt)*512 + lane*8]
__global__ __launch_bounds__(256) void pack_wih(
    const float* __restrict__ Wih_f, const float* __restrict__ Wih_b,
    unsigned short* __restrict__ wpi)
{
    int nt = blockIdx.x, dir = blockIdx.y;
    const float* W = dir ? Wih_b : Wih_f;
    int tid = threadIdx.x, lane = tid & 63, ktq = tid >> 6;
    int n = nt * 16 + (lane & 15);
    int kb = (lane >> 4) * 8;
    for (int kt = ktq; kt < 10; kt += 4) {
        int k0 = kt * 32 + kb;
        unsigned short tmp[8];
        #pragma unroll
        for (int u = 0; u < 8; ++u) {
            int k = k0 + u;
            tmp[u] = (k < D_DIM) ? f2bf(W[(size_t)n * D_DIM + k]) : (unsigned short)0;
        }
        *(uint4*)(wpi + (size_t)dir * 327680 + ((size_t)(nt * 10 + kt)) * 512 + lane * 8) = *(uint4*)tmp;
    }
}

// ---------------- pack conv weights ----------------
__global__ __launch_bounds__(256) void pack_conv(
    const float* __restrict__ Wih_c, const float* __restrict__ Whh_c, const float* __restrict__ b_c,
    unsigned short* __restrict__ Wpc)
{
    int row = blockIdx.x;
    unsigned short* o = Wpc + (size_t)row * KC_STRIDE;
    for (int k = threadIdx.x; k < KC_STRIDE; k += 256) {
        float v = 0.0f;
        if (k < HC)            v = Wih_c[row * HC + k];
        else if (k < 2 * HC)   v = Whh_c[row * HC + (k - HC)];
        else if (k == 1024)    v = b_c[row];
        o[k] = f2bf(v);
    }
}

// ---------------- msg_len ----------------
__global__ __launch_bounds__(256) void msg_len_kernel(const int* __restrict__ msgs,
                                                      int* __restrict__ mlen) {
    int n = blockIdx.x * 256 + threadIdx.x;
    if (n >= NMSG) return;
    int cnt = 0;
    #pragma unroll 8
    for (int l = 0; l < L_DIM; ++l) cnt += (msgs[n * L_DIM + l] != 0);
    mlen[n] = max(cnt, 1);
}

__global__ __launch_bounds__(256) void init_conv(float* __restrict__ ws) {
    unsigned i = blockIdx.x * 256u + threadIdx.x;
    if (i < 24576u) ws[OFF_HCONV + i] = 0.0f;
}

// ---------------- xg_vocab GEMM: E @ [Wih_f|Wih_b]^T + b, packed-W + bounced stores ----------------
#define EROW 328
__global__ __launch_bounds__(256) void xg_gemm(
    const float* __restrict__ E,
    const float* __restrict__ b_f, const float* __restrict__ b_b,
    const unsigned short* __restrict__ wpi,
    unsigned short* __restrict__ xgv)
{
    __shared__ __align__(16) unsigned short e_lds[32 * EROW];
    __shared__ __align__(16) float gbuf[32 * 264];
    const int w0 = blockIdx.x * 32;
    const int n0 = blockIdx.y * 256;
    const int dirb = n0 >> 10;
    const int nb = n0 & 1023;
    const float* bias = dirb ? b_b : b_f;

    const int tid = threadIdx.x, lane = tid & 63, wv = tid >> 6;
    const int l15 = lane & 15, kg = lane >> 4;

    for (int i = tid; i < 32 * 320; i += 256) {
        int r = i / 320, k = i - r * 320;
        float v = (k < D_DIM) ? E[(size_t)(w0 + r) * D_DIM + k] : 0.0f;
        e_lds[r * EROW + k] = f2bf(v);
    }
    __syncthreads();

    const unsigned short* wb = wpi + (size_t)dirb * 327680;
    const f4v zf = {0.0f, 0.0f, 0.0f, 0.0f};
    f4v acc[2][4];
    #pragma unroll
    for (int m = 0; m < 2; ++m)
        #pragma unroll
        for (int q = 0; q < 4; ++q) acc[m][q] = zf;

    for (int kt = 0; kt < 10; ++kt) {
        s8v a0 = *(const s8v*)&e_lds[l15 * EROW + kt * 32 + kg * 8];
        s8v a1 = *(const s8v*)&e_lds[(16 + l15) * EROW + kt * 32 + kg * 8];
        #pragma unroll
        for (int q = 0; q < 4; ++q) {
            int ntg = (nb >> 4) + wv * 4 + q;
            s8v b = *(const s8v*)(wb + ((size_t)(ntg * 10 + kt)) * 512 + lane * 8);
            acc[0][q] = MFMA(a0, b, acc[0][q]);
            acc[1][q] = MFMA(a1, b, acc[1][q]);
        }
    }

    #pragma unroll
    for (int q = 0; q < 4; ++q) {
        int col = (wv * 4 + q) * 16 + l15;
        float bv = bias[nb + col];
        #pragma unroll
        for (int m = 0; m < 2; ++m)
            #pragma unroll
            for (int r = 0; r < 4; ++r)
                gbuf[(m * 16 + kg * 4 + r) * 264 + col] = acc[m][q][r] + bv;
    }
    __syncthreads();
    {
        int row = tid >> 3, ch = tid & 7;
        unsigned short tmp[32];
        #pragma unroll
        for (int cc = 0; cc < 32; ++cc) tmp[cc] = f2bf(gbuf[row * 264 + ch * 32 + cc]);
        uint4* dst = (uint4*)(xgv + ((size_t)dirb * VOCAB + w0 + row) * 1024 + nb + ch * 32);
        const uint4* s4 = (const uint4*)tmp;
        #pragma unroll
        for (int u = 0; u < 4; ++u) dst[u] = s4[u];
    }
}

// ---------------- persistent word biLSTM: 256 blocks x 16 seqs, dbuf gload_lds ----------------
#define XGS  1032
#define HROW 264
__global__ __launch_bounds__(512) void word_lstm(
    const int* __restrict__ msgs, const int* __restrict__ mlen,
    const unsigned short* __restrict__ xgv,
    const unsigned short* __restrict__ whh,
    unsigned short* __restrict__ enc_bf)
{
    __shared__ __align__(16) unsigned short xg_lds[2][16 * XGS];
    __shared__ __align__(16) unsigned short h_lds[16 * HROW];
    __shared__ int tok_s[16 * 64];
    __shared__ int len_s[16];

    const int mg = blockIdx.x >> 1, dir = blockIdx.x & 1;
    const int tid = threadIdx.x, lane = tid & 63, wv = tid >> 6;
    const int l15 = lane & 15, kg = lane >> 4;

    for (int i = tid; i < 16 * 64; i += 512) tok_s[i] = msgs[mg * 16 * 64 + i];
    if (tid < 16) len_s[tid] = mlen[mg * 16 + tid];
    for (int i = tid; i < 16 * HROW; i += 512) h_lds[i] = 0;
    __syncthreads();

    const unsigned short* xv = xgv + (size_t)dir * VOCAB * 1024;
    const unsigned short* wb = whh + (size_t)dir * 262144;

    int lens[4];
    #pragma unroll
    for (int r = 0; r < 4; ++r) lens[r] = len_s[kg * 4 + r];

    float c_st[2][4], rm[2][4];
    #pragma unroll
    for (int q = 0; q < 2; ++q)
        #pragma unroll
        for (int r = 0; r < 4; ++r) { c_st[q][r] = 0.0f; rm[q][r] = -INFINITY; }

    // prologue: prefetch t=0 into buf0 (each wave owns rows wv*2, wv*2+1)
    #pragma unroll
    for (int rr = 0; rr < 2; ++rr) {
        int row = wv * 2 + rr;
        int tt = dir ? (len_s[row] - 1) : 0;
        if (tt < 0) tt = 0;
        const unsigned short* src = xv + (size_t)tok_s[row * 64 + tt] * 1024 + lane * 8;
        gload16(src,       &xg_lds[0][row * XGS]);
        gload16(src + 512, &xg_lds[0][row * XGS + 512]);
    }

    for (int t = 0; t < L_DIM; ++t) {
        __syncthreads();               // prefetch drained; h(t-1) writes visible
        const int buf = t & 1;
        if (t < 63) {                  // prefetch t+1 into other buffer
            #pragma unroll
            for (int rr = 0; rr < 2; ++rr) {
                int row = wv * 2 + rr;
                int tn = t + 1;
                int tt = dir ? (len_s[row] - 1 - tn) : tn;
                if (tt < 0) tt = 0;
                const unsigned short* src = xv + (size_t)tok_s[row * 64 + tt] * 1024 + lane * 8;
                gload16(src,       &xg_lds[buf ^ 1][row * XGS]);
                gload16(src + 512, &xg_lds[buf ^ 1][row * XGS + 512]);
            }
        }

        // acc init from xg (C-fragment layout: row=kg*4+r, col=l15-based)
        f4v acc[2][4];
        #pragma unroll
        for (int q = 0; q < 2; ++q)
            #pragma unroll
            for (int g = 0; g < 4; ++g) {
                f4v v;
                #pragma unroll
                for (int r = 0; r < 4; ++r)
                    v[r] = bf2f(xg_lds[buf][(kg * 4 + r) * XGS + g * 256 + wv * 32 + q * 16 + l15]);
                acc[q][g] = v;
            }

        // gates += h @ Whh^T : M=16, N=256/wave, K=256
        for (int kt = 0; kt < 8; ++kt) {
            s8v a = *(const s8v*)&h_lds[l15 * HROW + kt * 32 + kg * 8];
            #pragma unroll
            for (int g = 0; g < 4; ++g)
                #pragma unroll
                for (int q = 0; q < 2; ++q) {
                    int nt = g * 16 + wv * 2 + q;
                    s8v b = *(const s8v*)(wb + ((size_t)(nt * 8 + kt)) * 512 + lane * 8);
                    acc[q][g] = MFMA(a, b, acc[q][g]);
                }
        }

        // cell update
        float hv[2][4];
        #pragma unroll
        for (int q = 0; q < 2; ++q)
            #pragma unroll
            for (int r = 0; r < 4; ++r) {
                float gi = acc[q][0][r], gf = acc[q][1][r], gc = acc[q][2][r], go = acc[q][3][r];
                float cn = sigm(gf) * c_st[q][r] + sigm(gi) * tanh_f(gc);
                float hn = sigm(go) * tanh_f(cn);
                hv[q][r] = hn;
                if (t < lens[r]) { c_st[q][r] = cn; rm[q][r] = fmaxf(rm[q][r], hn); }
                else             rm[q][r] = fmaxf(rm[q][r], 0.0f);
            }
        __syncthreads();               // all h_lds reads done
        #pragma unroll
        for (int q = 0; q < 2; ++q)
            #pragma unroll
            for (int r = 0; r < 4; ++r)
                if (t < lens[r])
                    h_lds[(kg * 4 + r) * HROW + wv * 32 + q * 16 + l15] = f2bf(hv[q][r]);
    }

    #pragma unroll
    for (int q = 0; q < 2; ++q)
        #pragma unroll
        for (int r = 0; r < 4; ++r)
            enc_bf[(size_t)(mg * 16 + kg * 4 + r) * HC + dir * HH + wv * 32 + q * 16 + l15] = f2bf(rm[q][r]);
}

// ---------------- conv-level LSTM step ----------------
__global__ __launch_bounds__(256) void conv_step(
    const unsigned short* __restrict__ Wpc,
    const unsigned short* __restrict__ enc_bf,
    const int* __restrict__ conv_len,
    unsigned short* __restrict__ h_bf,
    float* __restrict__ c_ws,
    float* __restrict__ co,
    int s)
{
    __shared__ unsigned short xh[32][KC_LDS];
    __shared__ float gbuf[4][32][16];

    const int tid = threadIdx.x;
    const int jb = blockIdx.x;
    const int lane = tid & 63, wv = tid >> 6;
    const int l15 = lane & 15, kg = lane >> 4;
    const int mt = wv & 1, gp = wv >> 1;

    {
        int b = tid >> 3, sub = tid & 7;
        const uint4* esrc = (const uint4*)(enc_bf + ((size_t)(s * B_DIM + b)) * HC);
        const uint4* hsrc = (const uint4*)(h_bf + (size_t)b * HC);
        uint4* dst  = (uint4*)(&xh[b][0]);
        uint4* dst2 = (uint4*)(&xh[b][512]);
        #pragma unroll
        for (int u = 0; u < 8; ++u) dst[sub + 8 * u]  = esrc[sub + 8 * u];
        #pragma unroll
        for (int u = 0; u < 8; ++u) dst2[sub + 8 * u] = hsrc[sub + 8 * u];
        if (sub == 0) {
            xh[b][1024] = (unsigned short)0x3F80;
            for (int k = 1025; k < KC_LDS; ++k) xh[b][k] = 0;
        }
    }
    __syncthreads();

    const s8v* ap  = (const s8v*)(&xh[mt * 16 + l15][0]) + kg;
    const s8v* bp0 = (const s8v*)(Wpc + (size_t)((gp * 2 + 0) * HC + jb * 16 + l15) * KC_STRIDE) + kg;
    const s8v* bp1 = (const s8v*)(Wpc + (size_t)((gp * 2 + 1) * HC + jb * 16 + l15) * KC_STRIDE) + kg;

    const f4v zf = {0.0f, 0.0f, 0.0f, 0.0f};
    f4v a0 = zf, a1 = zf;
    for (int kt = 0; kt < KC_TILES; ++kt) {
        s8v a = ap[kt * 4];
        a0 = MFMA(a, bp0[kt * 4], a0);
        a1 = MFMA(a, bp1[kt * 4], a1);
    }
    #pragma unroll
    for (int r = 0; r < 4; ++r) {
        int m = mt * 16 + kg * 4 + r;
        gbuf[gp * 2 + 0][m][l15] = a0[r];
        gbuf[gp * 2 + 1][m][l15] = a1[r];
    }
    __syncthreads();

    #pragma unroll
    for (int u = 0; u < 2; ++u) {
        int cell = tid + 256 * u;
        int b = cell >> 4, jj = cell & 15;
        int j = jb * 16 + jj;
        bool valid = s < conv_len[b];
        float g_i = gbuf[0][b][jj], g_f = gbuf[1][b][jj];
        float g_c = gbuf[2][b][jj], g_o = gbuf[3][b][jj];
        float cold = c_ws[b * HC + j];
        float cn = sigm(g_f) * cold + sigm(g_i) * tanh_f(g_c);
        float hn = sigm(g_o) * tanh_f(cn);
        float outv = 0.0f;
        if (valid) {
            c_ws[b * HC + j] = cn;
            h_bf[b * HC + j] = f2bf(hn);
            outv = hn;
        }
        co[((size_t)s * B_DIM + b) * HC + j] = outv;
    }
}

// ---------------- final projection ----------------
__global__ __launch_bounds__(256) void logits_kernel(
    const float* __restrict__ gfeat, const float* __restrict__ Wc, const float* __restrict__ bc,
    const float* __restrict__ co, float* __restrict__ out)
{
    int o = blockIdx.x * 4 + (threadIdx.x >> 6);
    int lane = threadIdx.x & 63;
    const float* row = co + (size_t)o * HC;
    float sum = 0.0f;
    #pragma unroll
    for (int u = 0; u < 8; ++u) sum += row[lane + 64 * u] * Wc[lane + 64 * u];
    if (lane < F_DIM) sum += gfeat[o * F_DIM + lane] * Wc[HC + lane];
    #pragma unroll
    for (int off = 32; off > 0; off >>= 1) sum += __shfl_down(sum, off, 64);
    if (lane == 0) out[o] = sum + bc[0];
}

extern "C" void kernel_launch(void* const* d_in, const int* in_sizes, int n_in,
                              void* d_out, int out_size, void* d_ws, size_t ws_size,
                              hipStream_t stream) {
    const int*   msgs    = (const int*)  d_in[0];
    const float* gfeat   = (const float*)d_in[1];
    const int*   convlen = (const int*)  d_in[2];
    const float* E       = (const float*)d_in[3];
    const float* Wih_f   = (const float*)d_in[4];
    const float* Whh_f   = (const float*)d_in[5];
    const float* b_f     = (const float*)d_in[6];
    const float* Wih_b   = (const float*)d_in[7];
    const float* Whh_b   = (const float*)d_in[8];
    const float* b_b     = (const float*)d_in[9];
    const float* Wih_c   = (const float*)d_in[10];
    const float* Whh_c   = (const float*)d_in[11];
    const float* b_c     = (const float*)d_in[12];
    const float* Wc      = (const float*)d_in[13];
    const float* bc      = (const float*)d_in[14];
    float* out = (float*)d_out;
    float* ws  = (float*)d_ws;

    unsigned short* xgv    = (unsigned short*)(ws + OFF_XGV);
    unsigned short* whh    = (unsigned short*)(ws + OFF_WHH);
    unsigned short* wpi    = (unsigned short*)(ws + OFF_WPI);
    unsigned short* Wpc    = (unsigned short*)(ws + OFF_WPC);
    unsigned short* enc_bf = (unsigned short*)(ws + OFF_ENCB);
    unsigned short* h_bf   = (unsigned short*)(ws + OFF_HCONV);
    float*          c_ws   = ws + OFF_CCONV;
    float*          co     = ws + OFF_CO;
    int*            mlen   = (int*)(ws + OFF_MLEN);

    pack_whh<<<dim3(64, 2), 256, 0, stream>>>(Whh_f, Whh_b, whh);
    pack_wih<<<dim3(64, 2), 256, 0, stream>>>(Wih_f, Wih_b, wpi);
    pack_conv<<<2048, 256, 0, stream>>>(Wih_c, Whh_c, b_c, Wpc);
    msg_len_kernel<<<NMSG / 256, 256, 0, stream>>>(msgs, mlen);
    init_conv<<<96, 256, 0, stream>>>(ws);
    xg_gemm<<<dim3(1000, 8), 256, 0, stream>>>(E, b_f, b_b, wpi, xgv);

    word_lstm<<<256, 512, 0, stream>>>(msgs, mlen, xgv, whh, enc_bf);

    for (int s = 0; s < S_DIM; ++s)
        conv_step<<<32, 256, 0, stream>>>(Wpc, enc_bf, convlen, h_bf, c_ws, co, s);

    logits_kernel<<<NMSG / 4, 256, 0, stream>>>(gfeat, Wc, bc, co, out);
}